// Round 4
// baseline (378.192 us; speedup 1.0000x reference)
//
#include <hip/hip_runtime.h>

// Problem constants (fixed by the reference)
constexpr int Bn = 4, Nn = 5000, Kd = 20, Hh = 128;
constexpr int Ee = Nn * Kd;   // 100000
constexpr int Ep1 = Ee + 1;   // padded rows per batch in iUe table

typedef __attribute__((ext_vector_type(8))) short bf16x8;
typedef __attribute__((ext_vector_type(4))) short bf16x4;
typedef __attribute__((ext_vector_type(4))) float f32x4;

__device__ __forceinline__ short f2bf(float f) {
  unsigned int u = __builtin_bit_cast(unsigned int, f);
  u += 0x7fffu + ((u >> 16) & 1u);  // RNE (finite inputs only)
  return (short)(u >> 16);
}

__device__ __forceinline__ bf16x8 cvt8(const float* __restrict__ p) {
  float4 lo = *reinterpret_cast<const float4*>(p);
  float4 hi = *reinterpret_cast<const float4*>(p + 4);
  bf16x8 r;
  r[0] = f2bf(lo.x); r[1] = f2bf(lo.y); r[2] = f2bf(lo.z); r[3] = f2bf(lo.w);
  r[4] = f2bf(hi.x); r[5] = f2bf(hi.y); r[6] = f2bf(hi.z); r[7] = f2bf(hi.w);
  return r;
}

__device__ __forceinline__ bf16x8 zero8() {
  bf16x8 r;
  #pragma unroll
  for (int i = 0; i < 8; ++i) r[i] = 0;
  return r;
}

__device__ __forceinline__ f32x4 bf4_to_f32(bf16x4 v) {
  f32x4 r;
  #pragma unroll
  for (int i = 0; i < 4; ++i) {
    unsigned int u = ((unsigned int)(unsigned short)v[i]) << 16;
    r[i] = __builtin_bit_cast(float, u);
  }
  return r;
}

// ---------------------------------------------------------------------------
// Kernel 0: convert weights to bf16, fused biases, iUe placeholder rows.
// ---------------------------------------------------------------------------
__global__ void __launch_bounds__(256) prep_kernel(
    const float* __restrict__ U_w, const float* __restrict__ iU_w,
    const float* __restrict__ Vf_w, const float* __restrict__ Vt_w,
    const float* __restrict__ U_b, const float* __restrict__ iU_b,
    const float* __restrict__ W_ph,
    short* __restrict__ Ubf, short* __restrict__ iUbf,
    short* __restrict__ Vfbf, short* __restrict__ Vtbf,
    float* __restrict__ biasA, float* __restrict__ biasB,
    short* __restrict__ iUe, int write_iue) {
  int t = blockIdx.x * blockDim.x + threadIdx.x;
  if (t < Hh * Hh) {
    Ubf[t]  = f2bf(U_w[t]);
    iUbf[t] = f2bf(iU_w[t]);
    Vfbf[t] = f2bf(Vf_w[t]);
    Vtbf[t] = f2bf(Vt_w[t]);
  }
  if (t < Hh) {
    biasA[t] = U_b[t] + iU_b[t];
    biasB[t] = U_b[t] + W_ph[t];
  }
  if (write_iue && t < Bn * Hh) {  // placeholder row E per batch = W_ph
    int b = t >> 7, h = t & 127;
    iUe[((size_t)b * Ep1 + Ee) * Hh + h] = f2bf(W_ph[h]);
  }
}

// ---------------------------------------------------------------------------
// Kernel 1: Vx_from = x @ Vf_w^T + b, Vx_to = x @ Vt_w^T + b (fp32 out).
// ---------------------------------------------------------------------------
__global__ void __launch_bounds__(256) vxproj_kernel(
    const float* __restrict__ x,
    const short* __restrict__ Vfbf, const short* __restrict__ Vtbf,
    const float* __restrict__ Vf_b, const float* __restrict__ Vt_b,
    float* __restrict__ VxF, float* __restrict__ VxT) {
  int wave = (int)((blockIdx.x * blockDim.x + threadIdx.x) >> 6);
  constexpr int NW = (Bn * Nn) / 16;  // 1250
  if (wave >= NW) return;
  int lane = threadIdx.x & 63;
  int r = lane & 15, kg = lane >> 4;
  int row0 = wave * 16;
  const float* xrow = x + (size_t)(row0 + r) * Hh;

  f32x4 accF[8], accT[8];
  #pragma unroll
  for (int ht = 0; ht < 8; ++ht) {
    accF[ht] = (f32x4)(0.0f);
    accT[ht] = (f32x4)(0.0f);
  }

  #pragma unroll
  for (int kk = 0; kk < 4; ++kk) {
    int k0 = kk * 32 + kg * 8;
    bf16x8 a = cvt8(xrow + k0);
    #pragma unroll
    for (int ht = 0; ht < 8; ++ht) {
      bf16x8 bF = *reinterpret_cast<const bf16x8*>(Vfbf + (ht * 16 + r) * Hh + k0);
      bf16x8 bT = *reinterpret_cast<const bf16x8*>(Vtbf + (ht * 16 + r) * Hh + k0);
      accF[ht] = __builtin_amdgcn_mfma_f32_16x16x32_bf16(a, bF, accF[ht], 0, 0, 0);
      accT[ht] = __builtin_amdgcn_mfma_f32_16x16x32_bf16(a, bT, accT[ht], 0, 0, 0);
    }
  }

  #pragma unroll
  for (int ht = 0; ht < 8; ++ht) {
    int h = ht * 16 + r;
    float bf = Vf_b[h], bt = Vt_b[h];
    #pragma unroll
    for (int i = 0; i < 4; ++i) {
      size_t row = (size_t)(row0 + kg * 4 + i);
      VxF[row * Hh + h] = accF[ht][i] + bf;
      VxT[row * Hh + h] = accT[ht][i] + bt;
    }
  }
}

// ---------------------------------------------------------------------------
// Kernel 2 (plan B): iUe[b, j, :] = bf16( e[b,j]·iU_w^T + iU_b ).
// Coalesced stream GEMM. Wave = 16 e-rows x 128 h. D: col = e-row, row = h.
// ---------------------------------------------------------------------------
__global__ void __launch_bounds__(256) invproj_kernel(
    const float* __restrict__ e, const short* __restrict__ iUbf,
    const float* __restrict__ iU_b, short* __restrict__ iUe) {
  int wave = (int)((blockIdx.x * blockDim.x + threadIdx.x) >> 6);
  if (wave >= (Bn * Ee) / 16) return;  // 25000
  int lane = threadIdx.x & 63;
  int c = lane & 15, kg = lane >> 4;
  int row0 = wave * 16;               // batch-aligned: E % 16 == 0
  int b = row0 / Ee;
  int gr = row0 + c;                  // this lane's e-row (B-operand column)
  const float* erow = e + (size_t)gr * Hh;

  bf16x8 bfrag[4];
  #pragma unroll
  for (int kk = 0; kk < 4; ++kk) bfrag[kk] = cvt8(erow + kk * 32 + kg * 8);

  f32x4 acc[8];
  #pragma unroll
  for (int ht = 0; ht < 8; ++ht) acc[ht] = (f32x4)(0.0f);

  #pragma unroll
  for (int kk = 0; kk < 4; ++kk) {
    int k0 = kk * 32 + kg * 8;
    #pragma unroll
    for (int ht = 0; ht < 8; ++ht) {
      bf16x8 w = *reinterpret_cast<const bf16x8*>(iUbf + (ht * 16 + c) * Hh + k0);
      acc[ht] = __builtin_amdgcn_mfma_f32_16x16x32_bf16(w, bfrag[kk], acc[ht], 0, 0, 0);
    }
  }

  short* drow = iUe + (size_t)(gr + b) * Hh;  // b*Ep1 + (gr - b*Ee) == gr + b
  #pragma unroll
  for (int ht = 0; ht < 8; ++ht) {
    int h0 = ht * 16 + kg * 4;
    f32x4 bb = *reinterpret_cast<const f32x4*>(iU_b + h0);
    bf16x4 o;
    #pragma unroll
    for (int i = 0; i < 4; ++i) o[i] = f2bf(acc[ht][i] + bb[i]);
    *reinterpret_cast<bf16x4*>(drow + h0) = o;
  }
}

// ---------------------------------------------------------------------------
// Kernel 3 (plan B): main per-edge kernel. Wave = 16 edges x 128 h.
// U weights from 32KB L1-resident global table; no LDS, no barrier.
// ---------------------------------------------------------------------------
__global__ void __launch_bounds__(256, 4) edge_main_kernel(
    const float* __restrict__ e,
    const int* __restrict__ edge_index,
    const int* __restrict__ inv_edge_index,
    const short* __restrict__ Ubf, const float* __restrict__ U_b,
    const short* __restrict__ iUe,
    const float* __restrict__ VxF, const float* __restrict__ VxT,
    float* __restrict__ out) {
  int wave = (int)((blockIdx.x * blockDim.x + threadIdx.x) >> 6);
  if (wave >= (Bn * Ee) / 16) return;  // 25000
  int lane = threadIdx.x & 63;
  int c = lane & 15, kg = lane >> 4;
  int row0 = wave * 16;
  int b = row0 / Ee;
  int gr = row0 + c;                   // global edge row
  int j = gr - b * Ee;                 // edge within batch
  const size_t ebase = (size_t)b * Ee;

  int i2 = inv_edge_index[ebase + j];  // 0..E (E = placeholder row)
  int ei = edge_index[ebase + j];

  const float* erow = e + (size_t)gr * Hh;
  bf16x8 a[4];
  #pragma unroll
  for (int kk = 0; kk < 4; ++kk) a[kk] = cvt8(erow + kk * 32 + kg * 8);

  f32x4 acc[8];
  #pragma unroll
  for (int ht = 0; ht < 8; ++ht) acc[ht] = (f32x4)(0.0f);

  #pragma unroll
  for (int kk = 0; kk < 4; ++kk) {
    int k0 = kk * 32 + kg * 8;
    #pragma unroll
    for (int ht = 0; ht < 8; ++ht) {
      bf16x8 w = *reinterpret_cast<const bf16x8*>(Ubf + (ht * 16 + c) * Hh + k0);
      acc[ht] = __builtin_amdgcn_mfma_f32_16x16x32_bf16(w, a[kk], acc[ht], 0, 0, 0);
    }
  }

  // Epilogue: lane holds edge gr (col c), rows h = ht*16 + kg*4 .. +3.
  const short* grow = iUe + ((size_t)b * Ep1 + i2) * Hh;
  const float* vt = VxT + ((size_t)b * Nn + ei) * Hh;
  const float* vf = VxF + ((size_t)b * Nn + j / Kd) * Hh;
  float* orow = out + (size_t)gr * Hh;
  #pragma unroll
  for (int ht = 0; ht < 8; ++ht) {
    int h0 = ht * 16 + kg * 4;
    f32x4 ub4 = *reinterpret_cast<const f32x4*>(U_b + h0);
    f32x4 g4 = bf4_to_f32(*reinterpret_cast<const bf16x4*>(grow + h0));
    f32x4 vt4 = *reinterpret_cast<const f32x4*>(vt + h0);
    f32x4 vf4 = *reinterpret_cast<const f32x4*>(vf + h0);
    f32x4 r = acc[ht] + ub4 + g4 + vt4 + vf4;
    *reinterpret_cast<f32x4*>(orow + h0) = r;
  }
}

// ---------------------------------------------------------------------------
// Fallback (verified round-3 path), used only if ws_size is too small.
// ---------------------------------------------------------------------------
__global__ void __launch_bounds__(512, 4) edge_kernel_fb(
    const float* __restrict__ e,
    const int* __restrict__ edge_index,
    const int* __restrict__ inv_edge_index,
    const short* __restrict__ Ubf, const short* __restrict__ iUbf,
    const float* __restrict__ biasA, const float* __restrict__ biasB,
    const float* __restrict__ VxF, const float* __restrict__ VxT,
    float* __restrict__ out) {
  __shared__ short wlds[2 * Hh * Hh];
  #pragma unroll
  for (int it = 0; it < 8; ++it) {
    int idx = it * 512 + (int)threadIdx.x;
    int m = idx >> 11;
    int rr = idx & 2047;
    int h = rr >> 4, kb = rr & 15;
    const short* src = (m ? iUbf : Ubf) + h * Hh + kb * 8;
    bf16x8 v = *reinterpret_cast<const bf16x8*>(src);
    int dst = m * (Hh * Hh) + h * Hh + ((kb ^ (h & 15)) << 3);
    *reinterpret_cast<bf16x8*>(wlds + dst) = v;
  }
  __syncthreads();

  int wv = (int)((blockIdx.x * blockDim.x + threadIdx.x) >> 6);
  if (wv < Bn * (Ee / 32)) {
    int lane = threadIdx.x & 63;
    int c = lane & 15, kg = lane >> 4;
    constexpr int WPB = Ee / 32;
    int b = wv / WPB;
    int j0 = (wv % WPB) * 32;
    const size_t ebase = (size_t)b * Ee;
    const float* ebat = e + ebase * Hh;

    int jc[2] = {j0 + c, j0 + 16 + c};
    int i2[2], ei[2];
    bool ph[2];
    #pragma unroll
    for (int et = 0; et < 2; ++et) {
      i2[et] = inv_edge_index[ebase + jc[et]];
      ei[et] = edge_index[ebase + jc[et]];
      ph[et] = (i2[et] == Ee);
    }

    f32x4 acc[2][8];
    #pragma unroll
    for (int et = 0; et < 2; ++et)
      #pragma unroll
      for (int ht = 0; ht < 8; ++ht) acc[et][ht] = (f32x4)(0.0f);

    #pragma unroll
    for (int kk = 0; kk < 4; ++kk) {
      int k0 = kk * 32 + kg * 8;
      bf16x8 a1[2], a2[2];
      #pragma unroll
      for (int et = 0; et < 2; ++et) {
        int row2 = ph[et] ? 0 : i2[et];
        a1[et] = cvt8(ebat + (size_t)jc[et] * Hh + k0);
        bf16x8 t = cvt8(ebat + (size_t)row2 * Hh + k0);
        a2[et] = ph[et] ? zero8() : t;
      }
      #pragma unroll
      for (int ht = 0; ht < 8; ++ht) {
        int h = ht * 16 + c;
        int off = h * Hh + ((((kk << 2) + kg) ^ (h & 15)) << 3);
        bf16x8 wu = *reinterpret_cast<const bf16x8*>(wlds + off);
        bf16x8 wi = *reinterpret_cast<const bf16x8*>(wlds + Hh * Hh + off);
        #pragma unroll
        for (int et = 0; et < 2; ++et) {
          acc[et][ht] = __builtin_amdgcn_mfma_f32_16x16x32_bf16(wu, a1[et], acc[et][ht], 0, 0, 0);
          acc[et][ht] = __builtin_amdgcn_mfma_f32_16x16x32_bf16(wi, a2[et], acc[et][ht], 0, 0, 0);
        }
      }
    }

    #pragma unroll
    for (int et = 0; et < 2; ++et) {
      const float* vt = VxT + ((size_t)b * Nn + ei[et]) * Hh;
      const float* vf = VxF + ((size_t)b * Nn + jc[et] / Kd) * Hh;
      float* orow = out + (ebase + (size_t)jc[et]) * Hh;
      #pragma unroll
      for (int ht = 0; ht < 8; ++ht) {
        int h0 = ht * 16 + kg * 4;
        f32x4 bA = *reinterpret_cast<const f32x4*>(biasA + h0);
        f32x4 bB = *reinterpret_cast<const f32x4*>(biasB + h0);
        f32x4 vt4 = *reinterpret_cast<const f32x4*>(vt + h0);
        f32x4 vf4 = *reinterpret_cast<const f32x4*>(vf + h0);
        f32x4 r = acc[et][ht] + (ph[et] ? bB : bA) + vt4 + vf4;
        *reinterpret_cast<f32x4*>(orow + h0) = r;
      }
    }
  }
}

extern "C" void kernel_launch(void* const* d_in, const int* in_sizes, int n_in,
                              void* d_out, int out_size, void* d_ws, size_t ws_size,
                              hipStream_t stream) {
  const float* x   = (const float*)d_in[0];
  const float* e   = (const float*)d_in[1];
  const int* edge_index = (const int*)d_in[2];
  const int* inv_edge_index = (const int*)d_in[3];
  const float* U_w  = (const float*)d_in[4];
  const float* U_b  = (const float*)d_in[5];
  const float* Vf_w = (const float*)d_in[6];
  const float* Vf_b = (const float*)d_in[7];
  const float* Vt_w = (const float*)d_in[8];
  const float* Vt_b = (const float*)d_in[9];
  const float* iU_w = (const float*)d_in[10];
  const float* iU_b = (const float*)d_in[11];
  const float* W_ph = (const float*)d_in[12];
  float* out = (float*)d_out;

  // Workspace layout
  float* VxF   = (float*)d_ws;                         // B*N*H floats
  float* VxT   = VxF + (size_t)Bn * Nn * Hh;           // B*N*H floats
  float* biasA = VxT + (size_t)Bn * Nn * Hh;           // 128
  float* biasB = biasA + Hh;                           // 128
  short* Ubf   = (short*)(biasB + Hh);                 // 16384 shorts each
  short* iUbf  = Ubf + Hh * Hh;
  short* Vfbf  = iUbf + Hh * Hh;
  short* Vtbf  = Vfbf + Hh * Hh;
  short* iUe   = Vtbf + Hh * Hh;                       // Bn*Ep1*Hh shorts

  size_t need = (size_t)((char*)(iUe + (size_t)Bn * Ep1 * Hh) - (char*)d_ws);
  int planB = (ws_size >= need) ? 1 : 0;

  prep_kernel<<<dim3(64), dim3(256), 0, stream>>>(
      U_w, iU_w, Vf_w, Vt_w, U_b, iU_b, W_ph, Ubf, iUbf, Vfbf, Vtbf,
      biasA, biasB, iUe, planB);

  vxproj_kernel<<<dim3(313), dim3(256), 0, stream>>>(
      x, Vfbf, Vtbf, Vf_b, Vt_b, VxF, VxT);

  if (planB) {
    int nblocks = (Bn * Ee) / 64;  // 6250 blocks of 256 threads (4 waves)
    invproj_kernel<<<dim3(nblocks), dim3(256), 0, stream>>>(e, iUbf, iU_b, iUe);
    edge_main_kernel<<<dim3(nblocks), dim3(256), 0, stream>>>(
        e, edge_index, inv_edge_index, Ubf, U_b, iUe, VxF, VxT, out);
  } else {
    int nwaves = Bn * (Ee / 32);
    int nblocks = (nwaves + 7) / 8;
    edge_kernel_fb<<<dim3(nblocks), dim3(512), 0, stream>>>(
        e, edge_index, inv_edge_index, Ubf, iUbf, biasA, biasB, VxF, VxT, out);
  }
}

// Round 5
// 183.620 us; speedup vs baseline: 2.0596x; 2.0596x over previous
//
#include <hip/hip_runtime.h>

// Problem constants (fixed by the reference)
constexpr int Bn = 4, Nn = 5000, Kd = 20, Hh = 128;
constexpr int Ee = Nn * Kd;  // 100000

typedef __attribute__((ext_vector_type(8))) short bf16x8;
typedef __attribute__((ext_vector_type(4))) float f32x4;

__device__ __forceinline__ short f2bf(float f) {
  unsigned int u = __builtin_bit_cast(unsigned int, f);
  u += 0x7fffu + ((u >> 16) & 1u);  // RNE (finite inputs only)
  return (short)(u >> 16);
}

__device__ __forceinline__ bf16x8 cvt8(const float* __restrict__ p) {
  float4 lo = *reinterpret_cast<const float4*>(p);
  float4 hi = *reinterpret_cast<const float4*>(p + 4);
  bf16x8 r;
  r[0] = f2bf(lo.x); r[1] = f2bf(lo.y); r[2] = f2bf(lo.z); r[3] = f2bf(lo.w);
  r[4] = f2bf(hi.x); r[5] = f2bf(hi.y); r[6] = f2bf(hi.z); r[7] = f2bf(hi.w);
  return r;
}

// ---------------------------------------------------------------------------
// Kernel 0: convert weights to bf16, fused biases, and a 128-float zero row
// (used as the gather target for placeholder edges -> no select in K-loop).
// ---------------------------------------------------------------------------
__global__ void __launch_bounds__(256) prep_kernel(
    const float* __restrict__ U_w, const float* __restrict__ iU_w,
    const float* __restrict__ Vf_w, const float* __restrict__ Vt_w,
    const float* __restrict__ U_b, const float* __restrict__ iU_b,
    const float* __restrict__ W_ph,
    short* __restrict__ Ubf, short* __restrict__ iUbf,
    short* __restrict__ Vfbf, short* __restrict__ Vtbf,
    float* __restrict__ biasA, float* __restrict__ biasB,
    float* __restrict__ zrow) {
  int t = blockIdx.x * blockDim.x + threadIdx.x;
  if (t < Hh * Hh) {
    Ubf[t]  = f2bf(U_w[t]);
    iUbf[t] = f2bf(iU_w[t]);
    Vfbf[t] = f2bf(Vf_w[t]);
    Vtbf[t] = f2bf(Vt_w[t]);
  }
  if (t < Hh) {
    biasA[t] = U_b[t] + iU_b[t];
    biasB[t] = U_b[t] + W_ph[t];
    zrow[t] = 0.0f;
  }
}

// ---------------------------------------------------------------------------
// Kernel 1: Vx_from = x @ Vf_w^T + b, Vx_to = x @ Vt_w^T + b (fp32 out).
// ---------------------------------------------------------------------------
__global__ void __launch_bounds__(256) vxproj_kernel(
    const float* __restrict__ x,
    const short* __restrict__ Vfbf, const short* __restrict__ Vtbf,
    const float* __restrict__ Vf_b, const float* __restrict__ Vt_b,
    float* __restrict__ VxF, float* __restrict__ VxT) {
  int wave = (int)((blockIdx.x * blockDim.x + threadIdx.x) >> 6);
  constexpr int NW = (Bn * Nn) / 16;  // 1250
  if (wave >= NW) return;
  int lane = threadIdx.x & 63;
  int r = lane & 15, kg = lane >> 4;
  int row0 = wave * 16;
  const float* xrow = x + (size_t)(row0 + r) * Hh;

  f32x4 accF[8], accT[8];
  #pragma unroll
  for (int ht = 0; ht < 8; ++ht) {
    accF[ht] = (f32x4)(0.0f);
    accT[ht] = (f32x4)(0.0f);
  }

  #pragma unroll
  for (int kk = 0; kk < 4; ++kk) {
    int k0 = kk * 32 + kg * 8;
    bf16x8 a = cvt8(xrow + k0);
    #pragma unroll
    for (int ht = 0; ht < 8; ++ht) {
      bf16x8 bF = *reinterpret_cast<const bf16x8*>(Vfbf + (ht * 16 + r) * Hh + k0);
      bf16x8 bT = *reinterpret_cast<const bf16x8*>(Vtbf + (ht * 16 + r) * Hh + k0);
      accF[ht] = __builtin_amdgcn_mfma_f32_16x16x32_bf16(a, bF, accF[ht], 0, 0, 0);
      accT[ht] = __builtin_amdgcn_mfma_f32_16x16x32_bf16(a, bT, accT[ht], 0, 0, 0);
    }
  }

  #pragma unroll
  for (int ht = 0; ht < 8; ++ht) {
    int h = ht * 16 + r;
    float bf = Vf_b[h], bt = Vt_b[h];
    #pragma unroll
    for (int i = 0; i < 4; ++i) {
      size_t row = (size_t)(row0 + kg * 4 + i);
      VxF[row * Hh + h] = accF[ht][i] + bf;
      VxT[row * Hh + h] = accT[ht][i] + bt;
    }
  }
}

// ---------------------------------------------------------------------------
// Kernel 2: main fused per-edge kernel (v5 = round-3 structure, de-spilled).
//   - launch_bounds(512,3): VGPR cap ~168 -> no spill, scheduler freedom
//   - all 8 gathered a2 fragments staged up-front (long-latency loads first)
//   - placeholder edges gather from a zero row (no select in K-loop)
//   - U/iU weights in XOR-swizzled LDS (verified conflict-free)
// One wave = 32 edges x 128 h. 8 waves/block.
// ---------------------------------------------------------------------------
__global__ void __launch_bounds__(512, 3) edge_kernel(
    const float* __restrict__ e,
    const int* __restrict__ edge_index,
    const int* __restrict__ inv_edge_index,
    const short* __restrict__ Ubf, const short* __restrict__ iUbf,
    const float* __restrict__ biasA, const float* __restrict__ biasB,
    const float* __restrict__ zrow,
    const float* __restrict__ VxF, const float* __restrict__ VxT,
    float* __restrict__ out) {
  __shared__ short wlds[2 * Hh * Hh];  // 64 KiB
  #pragma unroll
  for (int it = 0; it < 8; ++it) {
    int idx = it * 512 + (int)threadIdx.x;   // 0..4095 chunks of 16B
    int m = idx >> 11;
    int rr = idx & 2047;
    int h = rr >> 4, kb = rr & 15;
    const short* src = (m ? iUbf : Ubf) + h * Hh + kb * 8;
    bf16x8 v = *reinterpret_cast<const bf16x8*>(src);
    int dst = m * (Hh * Hh) + h * Hh + ((kb ^ (h & 15)) << 3);
    *reinterpret_cast<bf16x8*>(wlds + dst) = v;
  }
  __syncthreads();

  int wv = (int)((blockIdx.x * blockDim.x + threadIdx.x) >> 6);
  if (wv < Bn * (Ee / 32)) {
    int lane = threadIdx.x & 63;
    int c = lane & 15, kg = lane >> 4;
    constexpr int WPB = Ee / 32;  // 3125
    int b = wv / WPB;
    int j0 = (wv % WPB) * 32;
    const size_t ebase = (size_t)b * Ee;
    const float* ebat = e + ebase * Hh;

    int jc[2] = {j0 + c, j0 + 16 + c};
    int i2[2], ei[2];
    bool ph[2];
    const float* a2r[2];
    #pragma unroll
    for (int et = 0; et < 2; ++et) {
      i2[et] = inv_edge_index[ebase + jc[et]];
      ei[et] = edge_index[ebase + jc[et]];
      ph[et] = (i2[et] == Ee);
      a2r[et] = ph[et] ? zrow : (ebat + (size_t)i2[et] * Hh);
    }

    // Stage ALL gathered fragments first: longest-latency loads issue early.
    bf16x8 a2f[2][4];
    #pragma unroll
    for (int et = 0; et < 2; ++et)
      #pragma unroll
      for (int kk = 0; kk < 4; ++kk)
        a2f[et][kk] = cvt8(a2r[et] + kk * 32 + kg * 8);

    f32x4 acc[2][8];
    #pragma unroll
    for (int et = 0; et < 2; ++et)
      #pragma unroll
      for (int ht = 0; ht < 8; ++ht) acc[et][ht] = (f32x4)(0.0f);

    #pragma unroll
    for (int kk = 0; kk < 4; ++kk) {
      int k0 = kk * 32 + kg * 8;
      bf16x8 a1[2];
      #pragma unroll
      for (int et = 0; et < 2; ++et)
        a1[et] = cvt8(ebat + (size_t)jc[et] * Hh + k0);
      #pragma unroll
      for (int ht = 0; ht < 8; ++ht) {
        int h = ht * 16 + c;
        int off = h * Hh + ((((kk << 2) + kg) ^ (h & 15)) << 3);
        bf16x8 wu = *reinterpret_cast<const bf16x8*>(wlds + off);
        bf16x8 wi = *reinterpret_cast<const bf16x8*>(wlds + Hh * Hh + off);
        #pragma unroll
        for (int et = 0; et < 2; ++et) {
          acc[et][ht] = __builtin_amdgcn_mfma_f32_16x16x32_bf16(wu, a1[et], acc[et][ht], 0, 0, 0);
          acc[et][ht] = __builtin_amdgcn_mfma_f32_16x16x32_bf16(wi, a2f[et][kk], acc[et][ht], 0, 0, 0);
        }
      }
    }

    // Epilogue: D col = edge (lane&15), row h = ht*16 + kg*4 + i
    #pragma unroll
    for (int et = 0; et < 2; ++et) {
      const float* vt = VxT + ((size_t)b * Nn + ei[et]) * Hh;
      const float* vf = VxF + ((size_t)b * Nn + jc[et] / Kd) * Hh;
      float* orow = out + (ebase + (size_t)jc[et]) * Hh;
      #pragma unroll
      for (int ht = 0; ht < 8; ++ht) {
        int h0 = ht * 16 + kg * 4;
        f32x4 bA = *reinterpret_cast<const f32x4*>(biasA + h0);
        f32x4 bB = *reinterpret_cast<const f32x4*>(biasB + h0);
        f32x4 vt4 = *reinterpret_cast<const f32x4*>(vt + h0);
        f32x4 vf4 = *reinterpret_cast<const f32x4*>(vf + h0);
        f32x4 r = acc[et][ht] + (ph[et] ? bB : bA) + vt4 + vf4;
        *reinterpret_cast<f32x4*>(orow + h0) = r;
      }
    }
  }
}

extern "C" void kernel_launch(void* const* d_in, const int* in_sizes, int n_in,
                              void* d_out, int out_size, void* d_ws, size_t ws_size,
                              hipStream_t stream) {
  const float* x   = (const float*)d_in[0];
  const float* e   = (const float*)d_in[1];
  const int* edge_index = (const int*)d_in[2];
  const int* inv_edge_index = (const int*)d_in[3];
  const float* U_w  = (const float*)d_in[4];
  const float* U_b  = (const float*)d_in[5];
  const float* Vf_w = (const float*)d_in[6];
  const float* Vf_b = (const float*)d_in[7];
  const float* Vt_w = (const float*)d_in[8];
  const float* Vt_b = (const float*)d_in[9];
  const float* iU_w = (const float*)d_in[10];
  const float* iU_b = (const float*)d_in[11];
  const float* W_ph = (const float*)d_in[12];
  float* out = (float*)d_out;

  // Workspace layout
  float* VxF   = (float*)d_ws;                         // B*N*H floats
  float* VxT   = VxF + (size_t)Bn * Nn * Hh;           // B*N*H floats
  float* biasA = VxT + (size_t)Bn * Nn * Hh;           // 128
  float* biasB = biasA + Hh;                           // 128
  float* zrow  = biasB + Hh;                           // 128 (zero row)
  short* Ubf   = (short*)(zrow + Hh);                  // 16384 shorts each
  short* iUbf  = Ubf + Hh * Hh;
  short* Vfbf  = iUbf + Hh * Hh;
  short* Vtbf  = Vfbf + Hh * Hh;

  prep_kernel<<<dim3(64), dim3(256), 0, stream>>>(
      U_w, iU_w, Vf_w, Vt_w, U_b, iU_b, W_ph, Ubf, iUbf, Vfbf, Vtbf,
      biasA, biasB, zrow);

  vxproj_kernel<<<dim3(313), dim3(256), 0, stream>>>(
      x, Vfbf, Vtbf, Vf_b, Vt_b, VxF, VxT);

  int nwaves = Bn * (Ee / 32);                 // 12500
  int nblocks = (nwaves + 7) / 8;              // 1563 blocks of 512 threads
  edge_kernel<<<dim3(nblocks), dim3(512), 0, stream>>>(
      e, edge_index, inv_edge_index, Ubf, iUbf, biasA, biasB, zrow,
      VxF, VxT, out);
}

// Round 6
// 169.312 us; speedup vs baseline: 2.2337x; 1.0845x over previous
//
#include <hip/hip_runtime.h>

// Problem constants (fixed by the reference)
constexpr int Bn = 4, Nn = 5000, Kd = 20, Hh = 128;
constexpr int Ee = Nn * Kd;  // 100000

typedef __attribute__((ext_vector_type(8))) short bf16x8;
typedef __attribute__((ext_vector_type(4))) float f32x4;

__device__ __forceinline__ short f2bf(float f) {
  unsigned int u = __builtin_bit_cast(unsigned int, f);
  u += 0x7fffu + ((u >> 16) & 1u);  // RNE (finite inputs only)
  return (short)(u >> 16);
}

__device__ __forceinline__ bf16x8 cvt8(const float* __restrict__ p) {
  float4 lo = *reinterpret_cast<const float4*>(p);
  float4 hi = *reinterpret_cast<const float4*>(p + 4);
  bf16x8 r;
  r[0] = f2bf(lo.x); r[1] = f2bf(lo.y); r[2] = f2bf(lo.z); r[3] = f2bf(lo.w);
  r[4] = f2bf(hi.x); r[5] = f2bf(hi.y); r[6] = f2bf(hi.z); r[7] = f2bf(hi.w);
  return r;
}

// ---------------------------------------------------------------------------
// Kernel 0: bf16 weights, fused bias vectors, placeholder-correction row,
// and a zero row (gather target for placeholder edges).
//   biasA = U_b + iU_b            (folded into VxF table by vxproj)
//   corr  = W_ph - iU_b           (added for placeholder edges only)
// ---------------------------------------------------------------------------
__global__ void __launch_bounds__(256) prep_kernel(
    const float* __restrict__ U_w, const float* __restrict__ iU_w,
    const float* __restrict__ Vf_w, const float* __restrict__ Vt_w,
    const float* __restrict__ U_b, const float* __restrict__ iU_b,
    const float* __restrict__ W_ph,
    short* __restrict__ Ubf, short* __restrict__ iUbf,
    short* __restrict__ Vfbf, short* __restrict__ Vtbf,
    float* __restrict__ biasA, float* __restrict__ corr,
    float* __restrict__ zrow) {
  int t = blockIdx.x * blockDim.x + threadIdx.x;
  if (t < Hh * Hh) {
    Ubf[t]  = f2bf(U_w[t]);
    iUbf[t] = f2bf(iU_w[t]);
    Vfbf[t] = f2bf(Vf_w[t]);
    Vtbf[t] = f2bf(Vt_w[t]);
  }
  if (t < Hh) {
    biasA[t] = U_b[t] + iU_b[t];
    corr[t]  = W_ph[t] - iU_b[t];
    zrow[t]  = 0.0f;
  }
}

// ---------------------------------------------------------------------------
// Kernel 1: VxF = x @ Vf_w^T + (Vf_b + U_b + iU_b), VxT = x @ Vt_w^T + Vt_b.
// ---------------------------------------------------------------------------
__global__ void __launch_bounds__(256) vxproj_kernel(
    const float* __restrict__ x,
    const short* __restrict__ Vfbf, const short* __restrict__ Vtbf,
    const float* __restrict__ Vf_b, const float* __restrict__ Vt_b,
    const float* __restrict__ biasA,
    float* __restrict__ VxF, float* __restrict__ VxT) {
  int wave = (int)((blockIdx.x * blockDim.x + threadIdx.x) >> 6);
  constexpr int NW = (Bn * Nn) / 16;  // 1250
  if (wave >= NW) return;
  int lane = threadIdx.x & 63;
  int r = lane & 15, kg = lane >> 4;
  int row0 = wave * 16;
  const float* xrow = x + (size_t)(row0 + r) * Hh;

  f32x4 accF[8], accT[8];
  #pragma unroll
  for (int ht = 0; ht < 8; ++ht) {
    accF[ht] = (f32x4)(0.0f);
    accT[ht] = (f32x4)(0.0f);
  }

  #pragma unroll
  for (int kk = 0; kk < 4; ++kk) {
    int k0 = kk * 32 + kg * 8;
    bf16x8 a = cvt8(xrow + k0);
    #pragma unroll
    for (int ht = 0; ht < 8; ++ht) {
      bf16x8 bF = *reinterpret_cast<const bf16x8*>(Vfbf + (ht * 16 + r) * Hh + k0);
      bf16x8 bT = *reinterpret_cast<const bf16x8*>(Vtbf + (ht * 16 + r) * Hh + k0);
      accF[ht] = __builtin_amdgcn_mfma_f32_16x16x32_bf16(a, bF, accF[ht], 0, 0, 0);
      accT[ht] = __builtin_amdgcn_mfma_f32_16x16x32_bf16(a, bT, accT[ht], 0, 0, 0);
    }
  }

  #pragma unroll
  for (int ht = 0; ht < 8; ++ht) {
    int h = ht * 16 + r;
    float bf = Vf_b[h] + biasA[h];
    float bt = Vt_b[h];
    #pragma unroll
    for (int i = 0; i < 4; ++i) {
      size_t row = (size_t)(row0 + kg * 4 + i);
      VxF[row * Hh + h] = accF[ht][i] + bf;
      VxT[row * Hh + h] = accT[ht][i] + bt;
    }
  }
}

// ---------------------------------------------------------------------------
// Kernel 2: main fused per-edge kernel (v6).
//   - 16 edges/wave, 8 waves/block (512 thr), launch_bounds(512,4): VGPR<=128
//     -> 16 waves/CU (VGPR and LDS caps aligned)
//   - ALL global loads issue up-front: e-row frags + gathered frags + the
//     VxT/VxF rows, which go straight into the MFMA C-operand (C-init).
//   - K-loop is pure LDS + MFMA; epilogue is pure nontemporal stores.
//   - placeholder edges (i2==E, p~1e-5): gather zero row; exec-masked corr add.
// ---------------------------------------------------------------------------
__global__ void __launch_bounds__(512, 4) edge_kernel(
    const float* __restrict__ e,
    const int* __restrict__ edge_index,
    const int* __restrict__ inv_edge_index,
    const short* __restrict__ Ubf, const short* __restrict__ iUbf,
    const float* __restrict__ corr, const float* __restrict__ zrow,
    const float* __restrict__ VxF, const float* __restrict__ VxT,
    float* __restrict__ out) {
  __shared__ short wlds[2 * Hh * Hh];  // 64 KiB, XOR-swizzled chunks
  #pragma unroll
  for (int it = 0; it < 8; ++it) {
    int idx = it * 512 + (int)threadIdx.x;   // 0..4095 chunks of 16B
    int m = idx >> 11;
    int rr = idx & 2047;
    int h = rr >> 4, kb = rr & 15;
    const short* src = (m ? iUbf : Ubf) + h * Hh + kb * 8;
    bf16x8 v = *reinterpret_cast<const bf16x8*>(src);
    int dst = m * (Hh * Hh) + h * Hh + ((kb ^ (h & 15)) << 3);
    *reinterpret_cast<bf16x8*>(wlds + dst) = v;
  }
  __syncthreads();

  int wv = (int)((blockIdx.x * blockDim.x + threadIdx.x) >> 6);
  if (wv < (Bn * Ee) / 16) {  // 25000 waves
    int lane = threadIdx.x & 63;
    int c = lane & 15, kg = lane >> 4;
    constexpr int WPB = Ee / 16;  // 6250
    int b = wv / WPB;
    int j = (wv % WPB) * 16 + c;         // this lane's edge (B column c)
    const size_t ebase = (size_t)b * Ee;
    const float* ebat = e + ebase * Hh;

    int i2 = inv_edge_index[ebase + j];
    int ei = edge_index[ebase + j];
    bool ph = (i2 == Ee);
    const float* a1r = ebat + (size_t)j * Hh;
    const float* a2r = ph ? zrow : (ebat + (size_t)i2 * Hh);

    // Front-load ALL fragments (coalesced stream + gathered rows).
    bf16x8 a1f[4], a2f[4];
    #pragma unroll
    for (int kk = 0; kk < 4; ++kk) {
      int k0 = kk * 32 + kg * 8;
      a1f[kk] = cvt8(a1r + k0);
      a2f[kk] = cvt8(a2r + k0);
    }

    // C-init: acc = VxT[ei] + VxF[j/K] (biases pre-folded into VxF).
    const float* vt = VxT + ((size_t)b * Nn + ei) * Hh;
    const float* vf = VxF + ((size_t)b * Nn + j / Kd) * Hh;
    f32x4 acc[8];
    #pragma unroll
    for (int ht = 0; ht < 8; ++ht) {
      int h0 = ht * 16 + kg * 4;
      f32x4 vt4 = *reinterpret_cast<const f32x4*>(vt + h0);
      f32x4 vf4 = *reinterpret_cast<const f32x4*>(vf + h0);
      acc[ht] = vt4 + vf4;
    }
    if (ph) {  // rare (p ~ 1e-5): exec-masked, usually branched over
      #pragma unroll
      for (int ht = 0; ht < 8; ++ht) {
        int h0 = ht * 16 + kg * 4;
        acc[ht] += *reinterpret_cast<const f32x4*>(corr + h0);
      }
    }

    // K-loop: pure LDS reads + MFMA.
    #pragma unroll
    for (int kk = 0; kk < 4; ++kk) {
      #pragma unroll
      for (int ht = 0; ht < 8; ++ht) {
        int h = ht * 16 + c;
        int off = h * Hh + ((((kk << 2) + kg) ^ (h & 15)) << 3);
        bf16x8 wu = *reinterpret_cast<const bf16x8*>(wlds + off);
        bf16x8 wi = *reinterpret_cast<const bf16x8*>(wlds + Hh * Hh + off);
        acc[ht] = __builtin_amdgcn_mfma_f32_16x16x32_bf16(wu, a1f[kk], acc[ht], 0, 0, 0);
        acc[ht] = __builtin_amdgcn_mfma_f32_16x16x32_bf16(wi, a2f[kk], acc[ht], 0, 0, 0);
      }
    }

    // Epilogue: pure streaming stores (nontemporal: don't pollute L2).
    float* orow = out + (ebase + (size_t)j) * Hh;
    #pragma unroll
    for (int ht = 0; ht < 8; ++ht) {
      int h0 = ht * 16 + kg * 4;
      __builtin_nontemporal_store(acc[ht], reinterpret_cast<f32x4*>(orow + h0));
    }
  }
}

extern "C" void kernel_launch(void* const* d_in, const int* in_sizes, int n_in,
                              void* d_out, int out_size, void* d_ws, size_t ws_size,
                              hipStream_t stream) {
  const float* x   = (const float*)d_in[0];
  const float* e   = (const float*)d_in[1];
  const int* edge_index = (const int*)d_in[2];
  const int* inv_edge_index = (const int*)d_in[3];
  const float* U_w  = (const float*)d_in[4];
  const float* U_b  = (const float*)d_in[5];
  const float* Vf_w = (const float*)d_in[6];
  const float* Vf_b = (const float*)d_in[7];
  const float* Vt_w = (const float*)d_in[8];
  const float* Vt_b = (const float*)d_in[9];
  const float* iU_w = (const float*)d_in[10];
  const float* iU_b = (const float*)d_in[11];
  const float* W_ph = (const float*)d_in[12];
  float* out = (float*)d_out;

  // Workspace layout
  float* VxF   = (float*)d_ws;                         // B*N*H floats
  float* VxT   = VxF + (size_t)Bn * Nn * Hh;           // B*N*H floats
  float* biasA = VxT + (size_t)Bn * Nn * Hh;           // 128
  float* corr  = biasA + Hh;                           // 128
  float* zrow  = corr + Hh;                            // 128 (zero row)
  short* Ubf   = (short*)(zrow + Hh);                  // 16384 shorts each
  short* iUbf  = Ubf + Hh * Hh;
  short* Vfbf  = iUbf + Hh * Hh;
  short* Vtbf  = Vfbf + Hh * Hh;

  prep_kernel<<<dim3(64), dim3(256), 0, stream>>>(
      U_w, iU_w, Vf_w, Vt_w, U_b, iU_b, W_ph, Ubf, iUbf, Vfbf, Vtbf,
      biasA, corr, zrow);

  vxproj_kernel<<<dim3(313), dim3(256), 0, stream>>>(
      x, Vfbf, Vtbf, Vf_b, Vt_b, biasA, VxF, VxT);

  int nwaves = (Bn * Ee) / 16;                 // 25000
  int nblocks = nwaves / 8;                    // 3125 blocks of 512 threads
  edge_kernel<<<dim3(nblocks), dim3(512), 0, stream>>>(
      e, edge_index, inv_edge_index, Ubf, iUbf, corr, zrow, VxF, VxT, out);
}